// Round 8
// baseline (395.416 us; speedup 1.0000x reference)
//
#include <hip/hip_runtime.h>
#include <hip/hip_fp16.h>

#define B_ 16384
#define T_ 128
#define E_ 32
#define H_ 128
#define G3_ 384
#define V_ 30001
#define D_ 128
#define C_ 3

#define LOG2E 1.44269504088896340736f

typedef _Float16 f16;
typedef f16 f16x4 __attribute__((ext_vector_type(4)));
typedef f16 f16x8 __attribute__((ext_vector_type(8)));
typedef float f32x4 __attribute__((ext_vector_type(4)));
typedef unsigned int u32;

// ---- LDS layout (bytes), 512-thread block, 16 batch rows ----
#define HPITCH   272                 // h row pitch: 128 f16 + pad; 272B = 68 dw ≡ 4 (mod 32) rotates banks per row
#define H0_OFF   0                   // 16*272 = 4352
#define H1_OFF   4352
#define TOK_OFF  8704                // u32 byte-offsets, [t=128][r=16] = 8192
#define DBUF_OFF 16896               // head dbuf f32 [16][132] = 8448
#define LDS_TOTAL 25344

__device__ __forceinline__ float frcp_(float x)  { return __builtin_amdgcn_rcpf(x); }
__device__ __forceinline__ float fexp2_(float x) { return __builtin_amdgcn_exp2f(x); }

// lgkm-only barrier: drains LDS (h writes/reads) but leaves global gather
// loads in flight across the barrier (compiler inserts counted vmcnt before
// their USE next iteration). __syncthreads() would force vmcnt(0) drain of
// the prefetch every step -> gather latency on the critical path.
#define BAR_LGKM() asm volatile("s_waitcnt lgkmcnt(0)\n\ts_barrier" ::: "memory")

// ---------------- Kernel 1: pre-scaled table, [v][slot][c] ----------------
// embW[v*384 + g], g = slot*128 + c; slot 0=z,1=r (x -log2e, b1 folded),
// 2=h (x +2log2e, b1_h NOT folded -- it sits inside r*(.)).
#define K1_ROWS 8
__global__ __launch_bounds__(384) void embw_kernel(
    const float* __restrict__ emb,   // [V][32]
    const float* __restrict__ W,     // [32][384]
    const float* __restrict__ b,     // [2][384]
    f16* __restrict__ embW)          // [V][384] f16 pre-scaled
{
    __shared__ float sW[E_][G3_];
    __shared__ float sE[K1_ROWS][E_];
    const int g = threadIdx.x;           // 0..383
    #pragma unroll
    for (int e = 0; e < E_; ++e) sW[e][g] = W[e * G3_ + g];
    const int v0 = blockIdx.x * K1_ROWS;
    for (int idx = g; idx < K1_ROWS * E_; idx += 384) {
        int rr = idx >> 5, ee = idx & 31;
        int v = v0 + rr;
        sE[rr][ee] = (v < V_) ? emb[v * E_ + ee] : 0.f;
    }
    __syncthreads();
    // fold input bias b0 always; fold recurrent bias b1 for z,r slots only
    const float bg = b[g] + ((g < 256) ? b[G3_ + g] : 0.f);
    const float sc = (g >= 256) ? (2.f * LOG2E) : (-LOG2E);
    #pragma unroll
    for (int rr = 0; rr < K1_ROWS; ++rr) {
        int v = v0 + rr;
        if (v >= V_) break;
        float acc = bg;
        #pragma unroll
        for (int e = 0; e < E_; ++e) acc = fmaf(sE[rr][e], sW[e][g], acc);
        embW[(size_t)v * G3_ + g] = (f16)(acc * sc);
    }
}

// ---------------- Kernel 2: transposed-output MFMA GRU ----------------
// 1024 blocks x 512 threads (8 waves). Block owns 16 batch rows; wave w owns
// gate-cols [16w,16w+16). rec^T = U^T @ h^T:
//   A (persistent, 48 VGPR): lane l holds U[kt*32+q*8+j][gt*128 + w*16 + cl]
//   B (LDS): lane l holds h[batch=cl][kt*32+q*8+j]  (b128, pitch 272)
//   D: lane l reg i -> (gate-col w*16+4q+i, batch cl)
// C-operand carries x (z,r gates) / b1_h (h gate) -> no acc-init movs/adds.
__global__ __launch_bounds__(512, 4) void gru_mfma_kernel(
    const int*   __restrict__ tokens,  // [B][T]
    const f16*   __restrict__ embW,    // [V][384] f16 pre-scaled
    const float* __restrict__ U,       // [128][384]
    const float* __restrict__ b,       // [2][384]
    const float* __restrict__ W1,      // [128][128]
    const float* __restrict__ b1,      // [128]
    const float* __restrict__ Wout,    // [128][3]
    const float* __restrict__ bout,    // [3]
    float* __restrict__ out)           // [B][3]
{
    __shared__ char lds[LDS_TOTAL];
    const int tid = threadIdx.x;
    const int w   = tid >> 6;       // wave = 16-gate-col group, 0..7
    const int l   = tid & 63;
    const int cl  = l & 15;         // batch row owned by this lane
    const int q   = l >> 4;         // 0..3
    const int R0  = blockIdx.x * 16;
    const int c0  = w * 16 + 4 * q; // lane's 4 gate-cols base (within 128)

    // ---- stage token byte-offsets (tok*768 = f16 row bytes), [t][r] ----
    for (int idx = tid; idx < 16 * T_; idx += 512) {
        int r = idx >> 7, t = idx & 127;
        u32 tok = (u32)tokens[(size_t)(R0 + r) * T_ + t];
        *(u32*)(&lds[TOK_OFF + t * 64 + r * 4]) = tok * 768u;
    }
    // ---- zero h buffer 0 ----
    for (int idx = tid; idx < H1_OFF / 4; idx += 512)
        ((float*)(lds + H0_OFF))[idx] = 0.f;

    // ---- persistent U^T A-fragments, pre-scaled ----
    f16x8 Af[3][4];
    #pragma unroll
    for (int gt = 0; gt < 3; ++gt) {
        const float sc = (gt == 2) ? (2.f * LOG2E) : (-LOG2E);
        const int n = gt * 128 + w * 16 + cl;
        #pragma unroll
        for (int kt = 0; kt < 4; ++kt) {
            const int k0 = kt * 32 + q * 8;
            f16x8 fr;
            #pragma unroll
            for (int j = 0; j < 8; ++j)
                fr[j] = (f16)(U[(size_t)(k0 + j) * G3_ + n] * sc);
            Af[gt][kt] = fr;
        }
    }

    // h-gate recurrent bias (cannot fold into table: it sits inside r*(.))
    f32x4 bh4;
    #pragma unroll
    for (int i = 0; i < 4; ++i)
        bh4[i] = 2.f * LOG2E * b[G3_ + 256 + c0 + i];

    float hreg[4];
    #pragma unroll
    for (int i = 0; i < 4; ++i) hreg[i] = 0.f;

    __syncthreads();   // full barrier once (staging used global loads)

    const char* embWb = (const char*)embW;
    const int colb = c0 * 2;

    // prefetch t=0
    u32 offc = *(const u32*)(&lds[TOK_OFF + cl * 4]);
    f16x4 xzc = *(const f16x4*)(embWb + offc + colb);
    f16x4 xrc = *(const f16x4*)(embWb + offc + colb + 256);
    f16x4 xhc = *(const f16x4*)(embWb + offc + colb + 512);

    int cur = 0;
    for (int t = 0; t < T_; ++t) {
        const char* hb = lds + (cur ? H1_OFF : H0_OFF);
        char*       hn = lds + (cur ? H0_OFF : H1_OFF);

        // ---- (A) prefetch t+1 (stays in flight across the lgkm barrier) ----
        u32 offn = offc;
        f16x4 xzn = xzc, xrn = xrc, xhn = xhc;
        if (t + 1 < T_) {
            offn = *(const u32*)(&lds[TOK_OFF + (t + 1) * 64 + cl * 4]);
            xzn = *(const f16x4*)(embWb + offn + colb);
            xrn = *(const f16x4*)(embWb + offn + colb + 256);
            xhn = *(const f16x4*)(embWb + offn + colb + 512);
        }

        // ---- (B) B-fragments: h row cl ----
        const f16x8 bf0 = *(const f16x8*)(hb + cl * HPITCH + q * 16);
        const f16x8 bf1 = *(const f16x8*)(hb + cl * HPITCH + q * 16 + 64);
        const f16x8 bf2 = *(const f16x8*)(hb + cl * HPITCH + q * 16 + 128);
        const f16x8 bf3 = *(const f16x8*)(hb + cl * HPITCH + q * 16 + 192);

        // ---- (C) rec^T = U^T @ h^T, C-operand = x (z,r) / b1_h (h) ----
        f32x4 xz4, xr4;
        #pragma unroll
        for (int i = 0; i < 4; ++i) { xz4[i] = (float)xzc[i]; xr4[i] = (float)xrc[i]; }
        f32x4 accz = __builtin_amdgcn_mfma_f32_16x16x32_f16(Af[0][0], bf0, xz4, 0, 0, 0);
        f32x4 accr = __builtin_amdgcn_mfma_f32_16x16x32_f16(Af[1][0], bf0, xr4, 0, 0, 0);
        f32x4 acch = __builtin_amdgcn_mfma_f32_16x16x32_f16(Af[2][0], bf0, bh4, 0, 0, 0);
        accz = __builtin_amdgcn_mfma_f32_16x16x32_f16(Af[0][1], bf1, accz, 0, 0, 0);
        accr = __builtin_amdgcn_mfma_f32_16x16x32_f16(Af[1][1], bf1, accr, 0, 0, 0);
        acch = __builtin_amdgcn_mfma_f32_16x16x32_f16(Af[2][1], bf1, acch, 0, 0, 0);
        accz = __builtin_amdgcn_mfma_f32_16x16x32_f16(Af[0][2], bf2, accz, 0, 0, 0);
        accr = __builtin_amdgcn_mfma_f32_16x16x32_f16(Af[1][2], bf2, accr, 0, 0, 0);
        acch = __builtin_amdgcn_mfma_f32_16x16x32_f16(Af[2][2], bf2, acch, 0, 0, 0);
        accz = __builtin_amdgcn_mfma_f32_16x16x32_f16(Af[0][3], bf3, accz, 0, 0, 0);
        accr = __builtin_amdgcn_mfma_f32_16x16x32_f16(Af[1][3], bf3, accr, 0, 0, 0);
        acch = __builtin_amdgcn_mfma_f32_16x16x32_f16(Af[2][3], bf3, acch, 0, 0, 0);

        // ---- (D) gates (exp2-direct), single mask, packed b64 write ----
        f16x4 hv4;
        #pragma unroll
        for (int i = 0; i < 4; ++i) {
            const float z  = frcp_(1.f + fexp2_(accz[i]));
            const float r  = frcp_(1.f + fexp2_(accr[i]));
            const float hh = fmaf(-2.f, frcp_(1.f + fexp2_(fmaf(r, acch[i], (float)xhc[i]))), 1.f);
            const float hv = hreg[i];
            float nv = fmaf(z, hv - hh, hh);
            nv = (offc != 0u) ? nv : hv;
            hreg[i] = nv;
            hv4[i] = (f16)nv;
        }
        *(f16x4*)(hn + cl * HPITCH + colb) = hv4;

        // ---- (E) lgkm-only barrier ----
        BAR_LGKM();
        cur ^= 1;
        offc = offn; xzc = xzn; xrc = xrn; xhc = xhn;
    }
    // T_=128 even -> final h is in buffer 0 (last write drained by BAR_LGKM)

    // ---- head: d^T = W1^T @ h^T (swish), wave w owns d-cols [16w,16w+16) ----
    {
        f16x8 Wf[4];
        #pragma unroll
        for (int kt = 0; kt < 4; ++kt) {
            const int k0 = kt * 32 + q * 8;
            f16x8 fr;
            #pragma unroll
            for (int j = 0; j < 8; ++j)
                fr[j] = (f16)W1[(size_t)(k0 + j) * D_ + w * 16 + cl];
            Wf[kt] = fr;
        }
        const char* hb = lds + H0_OFF;
        f32x4 bd4;
        #pragma unroll
        for (int i = 0; i < 4; ++i) bd4[i] = b1[c0 + i];
        const f16x8 bf0 = *(const f16x8*)(hb + cl * HPITCH + q * 16);
        const f16x8 bf1 = *(const f16x8*)(hb + cl * HPITCH + q * 16 + 64);
        const f16x8 bf2 = *(const f16x8*)(hb + cl * HPITCH + q * 16 + 128);
        const f16x8 bf3 = *(const f16x8*)(hb + cl * HPITCH + q * 16 + 192);
        f32x4 dacc = __builtin_amdgcn_mfma_f32_16x16x32_f16(Wf[0], bf0, bd4, 0, 0, 0);
        dacc = __builtin_amdgcn_mfma_f32_16x16x32_f16(Wf[1], bf1, dacc, 0, 0, 0);
        dacc = __builtin_amdgcn_mfma_f32_16x16x32_f16(Wf[2], bf2, dacc, 0, 0, 0);
        dacc = __builtin_amdgcn_mfma_f32_16x16x32_f16(Wf[3], bf3, dacc, 0, 0, 0);
        f32x4 sw4;
        #pragma unroll
        for (int i = 0; i < 4; ++i) {
            const float v = dacc[i];
            sw4[i] = v * frcp_(1.f + fexp2_(-LOG2E * v));
        }
        *(f32x4*)(&lds[DBUF_OFF + cl * 528 + c0 * 4]) = sw4;
    }
    __syncthreads();

    // ---- logits + softmax: wave 0, 48 lanes = 16 rows x 3 classes ----
    if (w == 0 && l < 48) {
        const int row = l & 15, ci = l >> 4;
        float acc = bout[ci];
        #pragma unroll 4
        for (int k = 0; k < D_; ++k)
            acc = fmaf(*(const float*)(&lds[DBUF_OFF + row * 528 + k * 4]),
                       Wout[k * 3 + ci], acc);
        const float v0 = __shfl(acc, row);
        const float v1 = __shfl(acc, row + 16);
        const float v2 = __shfl(acc, row + 32);
        const float mx = fmaxf(v0, fmaxf(v1, v2));
        const float e0 = fexp2_(LOG2E * (v0 - mx));
        const float e1 = fexp2_(LOG2E * (v1 - mx));
        const float e2 = fexp2_(LOG2E * (v2 - mx));
        const float inv = frcp_(e0 + e1 + e2);
        const float mine = (ci == 0) ? e0 : (ci == 1) ? e1 : e2;
        out[(size_t)(R0 + row) * 3 + ci] = mine * inv;
    }
}

extern "C" void kernel_launch(void* const* d_in, const int* in_sizes, int n_in,
                              void* d_out, int out_size, void* d_ws, size_t ws_size,
                              hipStream_t stream) {
    (void)in_sizes; (void)n_in; (void)out_size; (void)ws_size;
    const int*   tokens = (const int*)d_in[0];
    const float* emb    = (const float*)d_in[1];
    const float* W      = (const float*)d_in[2];
    const float* U      = (const float*)d_in[3];
    const float* b      = (const float*)d_in[4];
    const float* W1     = (const float*)d_in[5];
    const float* b1     = (const float*)d_in[6];
    const float* Wout   = (const float*)d_in[7];
    const float* bout   = (const float*)d_in[8];
    float* out  = (float*)d_out;
    f16*   embW = (f16*)d_ws;   // [V][384] f16 = 23 MB scratch

    hipLaunchKernelGGL(embw_kernel, dim3((V_ + K1_ROWS - 1) / K1_ROWS), dim3(384), 0, stream,
                       emb, W, b, embW);
    hipLaunchKernelGGL(gru_mfma_kernel, dim3(B_ / 16), dim3(512), 0, stream,
                       tokens, embW, U, b, W1, b1, Wout, bout, out);
}

// Round 10
// 388.821 us; speedup vs baseline: 1.0170x; 1.0170x over previous
//
#include <hip/hip_runtime.h>
#include <hip/hip_fp16.h>

#define B_ 16384
#define T_ 128
#define E_ 32
#define H_ 128
#define G3_ 384
#define V_ 30001
#define D_ 128
#define C_ 3

#define LOG2E 1.44269504088896340736f

typedef _Float16 f16;
typedef f16 f16x4 __attribute__((ext_vector_type(4)));
typedef f16 f16x8 __attribute__((ext_vector_type(8)));
typedef float f32x4 __attribute__((ext_vector_type(4)));
typedef unsigned int u32;

// ---- LDS layout (bytes), 512-thread block, 32 batch rows = 2 groups of 16 ----
#define HPITCH   272                 // h row pitch (bank-rotating, b128-aligned)
#define H0_OFF   0                   // 16*272 = 4352
#define H1_OFF   4352
#define TOK_OFF  8704                // u32 offsets, [t=129][r=16] = 8256 B (t=128 zeroed)
#define GRP_BYTES 16960              // per-group slab (16B aligned)
#define DBUF_OFF  33920              // head dbuf f32 [32][132] = 16896
#define LDS_TOTAL 50816

__device__ __forceinline__ float frcp_(float x)  { return __builtin_amdgcn_rcpf(x); }
__device__ __forceinline__ float fexp2_(float x) { return __builtin_amdgcn_exp2f(x); }

// lgkm-only barrier: orders LDS h traffic; leaves global prefetch in flight.
#define BAR_LGKM() asm volatile("s_waitcnt lgkmcnt(0)\n\ts_barrier" ::: "memory")

// ---------------- Kernel 1: pre-scaled table, [v][slot][c] ----------------
// slot 0=z,1=r (x -log2e, b1 folded), 2=h (x +2log2e, b1_h not folded).
#define K1_ROWS 8
__global__ __launch_bounds__(384) void embw_kernel(
    const float* __restrict__ emb,   // [V][32]
    const float* __restrict__ W,     // [32][384]
    const float* __restrict__ b,     // [2][384]
    f16* __restrict__ embW)          // [V][384] f16 pre-scaled
{
    __shared__ float sW[E_][G3_];
    __shared__ float sE[K1_ROWS][E_];
    const int g = threadIdx.x;           // 0..383
    #pragma unroll
    for (int e = 0; e < E_; ++e) sW[e][g] = W[e * G3_ + g];
    const int v0 = blockIdx.x * K1_ROWS;
    for (int idx = g; idx < K1_ROWS * E_; idx += 384) {
        int rr = idx >> 5, ee = idx & 31;
        int v = v0 + rr;
        sE[rr][ee] = (v < V_) ? emb[v * E_ + ee] : 0.f;
    }
    __syncthreads();
    const float bg = b[g] + ((g < 256) ? b[G3_ + g] : 0.f);
    const float sc = (g >= 256) ? (2.f * LOG2E) : (-LOG2E);
    #pragma unroll
    for (int rr = 0; rr < K1_ROWS; ++rr) {
        int v = v0 + rr;
        if (v >= V_) break;
        float acc = bg;
        #pragma unroll
        for (int e = 0; e < E_; ++e) acc = fmaf(sE[rr][e], sW[e][g], acc);
        embW[(size_t)v * G3_ + g] = (f16)(acc * sc);
    }
}

// ---------------- Kernel 2: dual-stream transposed-output MFMA GRU ----------------
// 512 blocks x 512 threads (8 waves). Block owns 32 batch rows as TWO independent
// 16-row groups (A,B); wave w owns gate-cols [16w,16w+16) for both groups.
// Two independent step-chains per wave -> in-wave ILP fills the serial
// MFMA->trans latency chain. One lgkm barrier per step covers both groups.
//   A-frag (persistent, 48 regs): lane l holds sc*U[kt*32+q*8+j][gt*128+w*16+cl]
//   B-frag (LDS): lane l holds h[batch=cl][kt*32+q*8+j]  (b128, pitch 272)
//   D: lane l reg i -> (gate-col w*16+4q+i, batch cl)
__global__ __launch_bounds__(512, 3) void gru_mfma_kernel(
    const int*   __restrict__ tokens,  // [B][T]
    const f16*   __restrict__ embW,    // [V][384] f16 pre-scaled
    const float* __restrict__ U,       // [128][384]
    const float* __restrict__ b,       // [2][384]
    const float* __restrict__ W1,      // [128][128]
    const float* __restrict__ b1,      // [128]
    const float* __restrict__ Wout,    // [128][3]
    const float* __restrict__ bout,    // [3]
    float* __restrict__ out)           // [B][3]
{
    __shared__ char lds[LDS_TOTAL];
    const int tid = threadIdx.x;
    const int w   = tid >> 6;       // wave = 16-gate-col group, 0..7
    const int l   = tid & 63;
    const int cl  = l & 15;         // batch row (within group) owned by this lane
    const int q   = l >> 4;         // 0..3
    const int R0  = blockIdx.x * 32;
    const int c0  = w * 16 + 4 * q; // lane's 4 gate-cols base (within 128)

    char* gA = lds;
    char* gB = lds + GRP_BYTES;

    // ---- stage token byte-offsets (tok*768), [t][r], both groups ----
    for (int idx = tid; idx < 32 * T_; idx += 512) {
        int r = idx >> 7, t = idx & 127;
        u32 tok = (u32)tokens[(size_t)(R0 + r) * T_ + t];
        *(u32*)(&lds[(r >> 4) * GRP_BYTES + TOK_OFF + t * 64 + (r & 15) * 4]) = tok * 768u;
    }
    if (tid < 32)   // zero the t=128 prefetch row
        *(u32*)(&lds[(tid >> 4) * GRP_BYTES + TOK_OFF + 128 * 64 + (tid & 15) * 4]) = 0u;
    // ---- zero h buffer 0, both groups ----
    for (int idx = tid; idx < 1088; idx += 512) {
        ((float*)(gA + H0_OFF))[idx] = 0.f;
        ((float*)(gB + H0_OFF))[idx] = 0.f;
    }

    // ---- persistent U^T A-fragments, pre-scaled ----
    f16x8 Af[3][4];
    #pragma unroll
    for (int gt = 0; gt < 3; ++gt) {
        const float sc = (gt == 2) ? (2.f * LOG2E) : (-LOG2E);
        const int n = gt * 128 + w * 16 + cl;
        #pragma unroll
        for (int kt = 0; kt < 4; ++kt) {
            const int k0 = kt * 32 + q * 8;
            f16x8 fr;
            #pragma unroll
            for (int j = 0; j < 8; ++j)
                fr[j] = (f16)(U[(size_t)(k0 + j) * G3_ + n] * sc);
            Af[gt][kt] = fr;
        }
    }

    // h-gate recurrent bias (sits inside r*(.), can't fold into table)
    f32x4 bh4;
    #pragma unroll
    for (int i = 0; i < 4; ++i)
        bh4[i] = 2.f * LOG2E * b[G3_ + 256 + c0 + i];

    float hregA[4], hregB[4];
    #pragma unroll
    for (int i = 0; i < 4; ++i) { hregA[i] = 0.f; hregB[i] = 0.f; }

    __syncthreads();

    const char* embWb = (const char*)embW;
    const int colb = c0 * 2;

    // prefetch t=0, both groups
    u32 offA = *(const u32*)(gA + TOK_OFF + cl * 4);
    u32 offB = *(const u32*)(gB + TOK_OFF + cl * 4);
    f16x4 xzA = *(const f16x4*)(embWb + offA + colb);
    f16x4 xrA = *(const f16x4*)(embWb + offA + colb + 256);
    f16x4 xhA = *(const f16x4*)(embWb + offA + colb + 512);
    f16x4 xzB = *(const f16x4*)(embWb + offB + colb);
    f16x4 xrB = *(const f16x4*)(embWb + offB + colb + 256);
    f16x4 xhB = *(const f16x4*)(embWb + offB + colb + 512);

    int cur = 0;
    for (int t = 0; t < T_; ++t) {
        const char* hbA = gA + (cur ? H1_OFF : H0_OFF);
        char*       hnA = gA + (cur ? H0_OFF : H1_OFF);
        const char* hbB = gB + (cur ? H1_OFF : H0_OFF);
        char*       hnB = gB + (cur ? H0_OFF : H1_OFF);

        // ---- prefetch t+1 (TOK row 128 zeroed -> branch-free) ----
        const u32 offAn = *(const u32*)(gA + TOK_OFF + (t + 1) * 64 + cl * 4);
        const u32 offBn = *(const u32*)(gB + TOK_OFF + (t + 1) * 64 + cl * 4);
        const f16x4 xzAn = *(const f16x4*)(embWb + offAn + colb);
        const f16x4 xrAn = *(const f16x4*)(embWb + offAn + colb + 256);
        const f16x4 xhAn = *(const f16x4*)(embWb + offAn + colb + 512);
        const f16x4 xzBn = *(const f16x4*)(embWb + offBn + colb);
        const f16x4 xrBn = *(const f16x4*)(embWb + offBn + colb + 256);
        const f16x4 xhBn = *(const f16x4*)(embWb + offBn + colb + 512);

        // ---- B-fragments, both groups ----
        const f16x8 aA0 = *(const f16x8*)(hbA + cl * HPITCH + q * 16);
        const f16x8 aA1 = *(const f16x8*)(hbA + cl * HPITCH + q * 16 + 64);
        const f16x8 aA2 = *(const f16x8*)(hbA + cl * HPITCH + q * 16 + 128);
        const f16x8 aA3 = *(const f16x8*)(hbA + cl * HPITCH + q * 16 + 192);
        const f16x8 aB0 = *(const f16x8*)(hbB + cl * HPITCH + q * 16);
        const f16x8 aB1 = *(const f16x8*)(hbB + cl * HPITCH + q * 16 + 64);
        const f16x8 aB2 = *(const f16x8*)(hbB + cl * HPITCH + q * 16 + 128);
        const f16x8 aB3 = *(const f16x8*)(hbB + cl * HPITCH + q * 16 + 192);

        // ---- 24 MFMA: 6 independent 4-deep chains (3 gates x 2 groups) ----
        f32x4 xz4A, xr4A, xz4B, xr4B;
        #pragma unroll
        for (int i = 0; i < 4; ++i) {
            xz4A[i] = (float)xzA[i]; xr4A[i] = (float)xrA[i];
            xz4B[i] = (float)xzB[i]; xr4B[i] = (float)xrB[i];
        }
        f32x4 azA = __builtin_amdgcn_mfma_f32_16x16x32_f16(Af[0][0], aA0, xz4A, 0, 0, 0);
        f32x4 arA = __builtin_amdgcn_mfma_f32_16x16x32_f16(Af[1][0], aA0, xr4A, 0, 0, 0);
        f32x4 ahA = __builtin_amdgcn_mfma_f32_16x16x32_f16(Af[2][0], aA0, bh4,  0, 0, 0);
        f32x4 azB = __builtin_amdgcn_mfma_f32_16x16x32_f16(Af[0][0], aB0, xz4B, 0, 0, 0);
        f32x4 arB = __builtin_amdgcn_mfma_f32_16x16x32_f16(Af[1][0], aB0, xr4B, 0, 0, 0);
        f32x4 ahB = __builtin_amdgcn_mfma_f32_16x16x32_f16(Af[2][0], aB0, bh4,  0, 0, 0);
        azA = __builtin_amdgcn_mfma_f32_16x16x32_f16(Af[0][1], aA1, azA, 0, 0, 0);
        arA = __builtin_amdgcn_mfma_f32_16x16x32_f16(Af[1][1], aA1, arA, 0, 0, 0);
        ahA = __builtin_amdgcn_mfma_f32_16x16x32_f16(Af[2][1], aA1, ahA, 0, 0, 0);
        azB = __builtin_amdgcn_mfma_f32_16x16x32_f16(Af[0][1], aB1, azB, 0, 0, 0);
        arB = __builtin_amdgcn_mfma_f32_16x16x32_f16(Af[1][1], aB1, arB, 0, 0, 0);
        ahB = __builtin_amdgcn_mfma_f32_16x16x32_f16(Af[2][1], aB1, ahB, 0, 0, 0);
        azA = __builtin_amdgcn_mfma_f32_16x16x32_f16(Af[0][2], aA2, azA, 0, 0, 0);
        arA = __builtin_amdgcn_mfma_f32_16x16x32_f16(Af[1][2], aA2, arA, 0, 0, 0);
        ahA = __builtin_amdgcn_mfma_f32_16x16x32_f16(Af[2][2], aA2, ahA, 0, 0, 0);
        azB = __builtin_amdgcn_mfma_f32_16x16x32_f16(Af[0][2], aB2, azB, 0, 0, 0);
        arB = __builtin_amdgcn_mfma_f32_16x16x32_f16(Af[1][2], aB2, arB, 0, 0, 0);
        ahB = __builtin_amdgcn_mfma_f32_16x16x32_f16(Af[2][2], aB2, ahB, 0, 0, 0);
        azA = __builtin_amdgcn_mfma_f32_16x16x32_f16(Af[0][3], aA3, azA, 0, 0, 0);
        arA = __builtin_amdgcn_mfma_f32_16x16x32_f16(Af[1][3], aA3, arA, 0, 0, 0);
        ahA = __builtin_amdgcn_mfma_f32_16x16x32_f16(Af[2][3], aA3, ahA, 0, 0, 0);
        azB = __builtin_amdgcn_mfma_f32_16x16x32_f16(Af[0][3], aB3, azB, 0, 0, 0);
        arB = __builtin_amdgcn_mfma_f32_16x16x32_f16(Af[1][3], aB3, arB, 0, 0, 0);
        ahB = __builtin_amdgcn_mfma_f32_16x16x32_f16(Af[2][3], aB3, ahB, 0, 0, 0);

        // ---- gates, two interleavable trans-chains ----
        f16x4 hv4A, hv4B;
        #pragma unroll
        for (int i = 0; i < 4; ++i) {
            const float zA  = frcp_(1.f + fexp2_(azA[i]));
            const float rA  = frcp_(1.f + fexp2_(arA[i]));
            const float hhA = fmaf(-2.f, frcp_(1.f + fexp2_(fmaf(rA, ahA[i], (float)xhA[i]))), 1.f);
            const float hvA = hregA[i];
            float nvA = fmaf(zA, hvA - hhA, hhA);
            nvA = (offA != 0u) ? nvA : hvA;
            hregA[i] = nvA;
            hv4A[i] = (f16)nvA;

            const float zB  = frcp_(1.f + fexp2_(azB[i]));
            const float rB  = frcp_(1.f + fexp2_(arB[i]));
            const float hhB = fmaf(-2.f, frcp_(1.f + fexp2_(fmaf(rB, ahB[i], (float)xhB[i]))), 1.f);
            const float hvB = hregB[i];
            float nvB = fmaf(zB, hvB - hhB, hhB);
            nvB = (offB != 0u) ? nvB : hvB;
            hregB[i] = nvB;
            hv4B[i] = (f16)nvB;
        }
        *(f16x4*)(hnA + cl * HPITCH + colb) = hv4A;
        *(f16x4*)(hnB + cl * HPITCH + colb) = hv4B;

        BAR_LGKM();
        cur ^= 1;
        offA = offAn; xzA = xzAn; xrA = xrAn; xhA = xhAn;
        offB = offBn; xzB = xzBn; xrB = xrBn; xhB = xhBn;
    }
    // T_=128 even -> final h in buffer 0 of each group

    // ---- head: d^T = W1^T @ h^T (swish), both groups ----
    {
        f16x8 Wf[4];
        #pragma unroll
        for (int kt = 0; kt < 4; ++kt) {
            const int k0 = kt * 32 + q * 8;
            f16x8 fr;
            #pragma unroll
            for (int j = 0; j < 8; ++j)
                fr[j] = (f16)W1[(size_t)(k0 + j) * D_ + w * 16 + cl];
            Wf[kt] = fr;
        }
        f32x4 bd4;
        #pragma unroll
        for (int i = 0; i < 4; ++i) bd4[i] = b1[c0 + i];

        const char* hbA = gA + H0_OFF;
        const char* hbB = gB + H0_OFF;
        const f16x8 aA0 = *(const f16x8*)(hbA + cl * HPITCH + q * 16);
        const f16x8 aA1 = *(const f16x8*)(hbA + cl * HPITCH + q * 16 + 64);
        const f16x8 aA2 = *(const f16x8*)(hbA + cl * HPITCH + q * 16 + 128);
        const f16x8 aA3 = *(const f16x8*)(hbA + cl * HPITCH + q * 16 + 192);
        const f16x8 aB0 = *(const f16x8*)(hbB + cl * HPITCH + q * 16);
        const f16x8 aB1 = *(const f16x8*)(hbB + cl * HPITCH + q * 16 + 64);
        const f16x8 aB2 = *(const f16x8*)(hbB + cl * HPITCH + q * 16 + 128);
        const f16x8 aB3 = *(const f16x8*)(hbB + cl * HPITCH + q * 16 + 192);
        f32x4 dA = __builtin_amdgcn_mfma_f32_16x16x32_f16(Wf[0], aA0, bd4, 0, 0, 0);
        f32x4 dB = __builtin_amdgcn_mfma_f32_16x16x32_f16(Wf[0], aB0, bd4, 0, 0, 0);
        dA = __builtin_amdgcn_mfma_f32_16x16x32_f16(Wf[1], aA1, dA, 0, 0, 0);
        dB = __builtin_amdgcn_mfma_f32_16x16x32_f16(Wf[1], aB1, dB, 0, 0, 0);
        dA = __builtin_amdgcn_mfma_f32_16x16x32_f16(Wf[2], aA2, dA, 0, 0, 0);
        dB = __builtin_amdgcn_mfma_f32_16x16x32_f16(Wf[2], aB2, dB, 0, 0, 0);
        dA = __builtin_amdgcn_mfma_f32_16x16x32_f16(Wf[3], aA3, dA, 0, 0, 0);
        dB = __builtin_amdgcn_mfma_f32_16x16x32_f16(Wf[3], aB3, dB, 0, 0, 0);

        f32x4 swA, swB;
        #pragma unroll
        for (int i = 0; i < 4; ++i) {
            const float vA = dA[i];
            const float vB = dB[i];
            swA[i] = vA * frcp_(1.f + fexp2_(-LOG2E * vA));
            swB[i] = vB * frcp_(1.f + fexp2_(-LOG2E * vB));
        }
        *(f32x4*)(&lds[DBUF_OFF + cl * 528 + c0 * 4]) = swA;
        *(f32x4*)(&lds[DBUF_OFF + (16 + cl) * 528 + c0 * 4]) = swB;
    }
    __syncthreads();

    // ---- logits + softmax: wave 0 -> rows 0..15 (A), wave 1 -> rows 16..31 (B) ----
    if (w < 2 && l < 48) {
        const int row = (l & 15) + 16 * w;
        const int ci  = l >> 4;
        float acc = bout[ci];
        #pragma unroll 4
        for (int k = 0; k < D_; ++k)
            acc = fmaf(*(const float*)(&lds[DBUF_OFF + row * 528 + k * 4]),
                       Wout[k * 3 + ci], acc);
        const int rl = l & 15;
        const float v0 = __shfl(acc, rl);
        const float v1 = __shfl(acc, rl + 16);
        const float v2 = __shfl(acc, rl + 32);
        const float mx = fmaxf(v0, fmaxf(v1, v2));
        const float e0 = fexp2_(LOG2E * (v0 - mx));
        const float e1 = fexp2_(LOG2E * (v1 - mx));
        const float e2 = fexp2_(LOG2E * (v2 - mx));
        const float inv = frcp_(e0 + e1 + e2);
        const float mine = (ci == 0) ? e0 : (ci == 1) ? e1 : e2;
        out[(size_t)(R0 + row) * 3 + ci] = mine * inv;
    }
}

extern "C" void kernel_launch(void* const* d_in, const int* in_sizes, int n_in,
                              void* d_out, int out_size, void* d_ws, size_t ws_size,
                              hipStream_t stream) {
    (void)in_sizes; (void)n_in; (void)out_size; (void)ws_size;
    const int*   tokens = (const int*)d_in[0];
    const float* emb    = (const float*)d_in[1];
    const float* W      = (const float*)d_in[2];
    const float* U      = (const float*)d_in[3];
    const float* b      = (const float*)d_in[4];
    const float* W1     = (const float*)d_in[5];
    const float* b1     = (const float*)d_in[6];
    const float* Wout   = (const float*)d_in[7];
    const float* bout   = (const float*)d_in[8];
    float* out  = (float*)d_out;
    f16*   embW = (f16*)d_ws;   // [V][384] f16 = 23 MB scratch

    hipLaunchKernelGGL(embw_kernel, dim3((V_ + K1_ROWS - 1) / K1_ROWS), dim3(384), 0, stream,
                       emb, W, b, embW);
    hipLaunchKernelGGL(gru_mfma_kernel, dim3(B_ / 32), dim3(512), 0, stream,
                       tokens, embW, U, b, W1, b1, Wout, bout, out);
}